// Round 1
// baseline (632.218 us; speedup 1.0000x reference)
//
#include <hip/hip_runtime.h>

#define NODES 50000
#define FIN   256
#define FOUT  128
#define EPS   1e-5f
#define SLOPE 0.1f

// ---------------------------------------------------------------- degree count
__global__ void deg_kernel(const int* __restrict__ col, int E, int* __restrict__ deg) {
    int e = blockIdx.x * 256 + threadIdx.x;
    if (e < E) atomicAdd(&deg[col[e]], 1);
}

// ------------------------------------------------- exclusive scan (one block)
__global__ __launch_bounds__(1024) void scan_kernel(const int* __restrict__ deg,
                                                    int* __restrict__ offsets, int Nn) {
    __shared__ int sh[1024];
    const int t = threadIdx.x;
    const int C = (Nn + 1023) / 1024;
    const int start = t * C;
    int s = 0;
    for (int j = 0; j < C; ++j) {
        int i = start + j;
        if (i < Nn) s += deg[i];
    }
    sh[t] = s;
    __syncthreads();
    for (int off = 1; off < 1024; off <<= 1) {
        int v = (t >= off) ? sh[t - off] : 0;
        __syncthreads();
        sh[t] += v;
        __syncthreads();
    }
    int run = sh[t] - s;  // exclusive prefix of this thread's chunk
    for (int j = 0; j < C; ++j) {
        int i = start + j;
        if (i < Nn) { offsets[i] = run; run += deg[i]; }
    }
    if (t == 1023) offsets[Nn] = sh[1023];
}

// ---------------------------------------------------------------- dinv = (deg+1)^-1/2
__global__ void dinv_kernel(const int* __restrict__ deg, float* __restrict__ dinv, int Nn) {
    int i = blockIdx.x * 256 + threadIdx.x;
    if (i < Nn) dinv[i] = rsqrtf((float)(deg[i] + 1));
}

// ---------------------------------------------------------------- CSR fill (counting sort)
__global__ void fill_kernel(const int* __restrict__ row, const int* __restrict__ col, int E,
                            const int* __restrict__ offsets, int* __restrict__ cursor,
                            int* __restrict__ srcs) {
    int e = blockIdx.x * 256 + threadIdx.x;
    if (e < E) {
        int c = col[e];
        int p = offsets[c] + atomicAdd(&cursor[c], 1);
        srcs[p] = row[e];
    }
}

// ---------------------------------------------------------------- fp32 GEMM + bias
// C[M,128] = A[M,K] @ B[K,128] + bias ; BM=128, BN=128, BK=16, 8x8 microtile
template <int K>
__global__ __launch_bounds__(256) void gemm_bias_kernel(const float* __restrict__ A,
                                                        const float* __restrict__ B,
                                                        const float* __restrict__ bias,
                                                        float* __restrict__ C, int M) {
    __shared__ float Ast[16][132];  // [k][m], padded
    __shared__ float Bs[16][132];   // [k][n], padded
    const int tid = threadIdx.x;
    const int tx = tid & 15;
    const int ty = tid >> 4;
    const int m0 = blockIdx.x * 128;

    float acc[8][8];
#pragma unroll
    for (int i = 0; i < 8; ++i)
#pragma unroll
        for (int j = 0; j < 8; ++j) acc[i][j] = 0.f;

    const int ar   = tid >> 1;
    const int akc  = (tid & 1) * 8;
    const int arow = m0 + ar;
    const int bkr  = tid >> 4;
    const int bnc  = (tid & 15) * 8;

    for (int k0 = 0; k0 < K; k0 += 16) {
        float4 a0, a1;
        if (arow < M) {
            const float* p = A + (size_t)arow * K + k0 + akc;
            a0 = *(const float4*)p;
            a1 = *(const float4*)(p + 4);
        } else {
            a0 = make_float4(0.f, 0.f, 0.f, 0.f);
            a1 = a0;
        }
        Ast[akc + 0][ar] = a0.x; Ast[akc + 1][ar] = a0.y;
        Ast[akc + 2][ar] = a0.z; Ast[akc + 3][ar] = a0.w;
        Ast[akc + 4][ar] = a1.x; Ast[akc + 5][ar] = a1.y;
        Ast[akc + 6][ar] = a1.z; Ast[akc + 7][ar] = a1.w;

        const float* pb = B + (size_t)(k0 + bkr) * FOUT + bnc;
        float4 b0 = *(const float4*)pb;
        float4 b1 = *(const float4*)(pb + 4);
        *(float4*)&Bs[bkr][bnc]     = b0;
        *(float4*)&Bs[bkr][bnc + 4] = b1;

        __syncthreads();
#pragma unroll
        for (int kk = 0; kk < 16; ++kk) {
            float a[8], b[8];
            *(float4*)&a[0] = *(const float4*)&Ast[kk][ty * 8];
            *(float4*)&a[4] = *(const float4*)&Ast[kk][ty * 8 + 4];
            *(float4*)&b[0] = *(const float4*)&Bs[kk][tx * 8];
            *(float4*)&b[4] = *(const float4*)&Bs[kk][tx * 8 + 4];
#pragma unroll
            for (int i = 0; i < 8; ++i)
#pragma unroll
                for (int j = 0; j < 8; ++j) acc[i][j] = fmaf(a[i], b[j], acc[i][j]);
        }
        __syncthreads();
    }

    float bv[8];
#pragma unroll
    for (int j = 0; j < 8; ++j) bv[j] = bias[tx * 8 + j];
#pragma unroll
    for (int i = 0; i < 8; ++i) {
        int r = m0 + ty * 8 + i;
        if (r < M) {
            float4 o0, o1;
            o0.x = acc[i][0] + bv[0]; o0.y = acc[i][1] + bv[1];
            o0.z = acc[i][2] + bv[2]; o0.w = acc[i][3] + bv[3];
            o1.x = acc[i][4] + bv[4]; o1.y = acc[i][5] + bv[5];
            o1.z = acc[i][6] + bv[6]; o1.w = acc[i][7] + bv[7];
            float* pc = C + (size_t)r * FOUT + tx * 8;
            *(float4*)pc       = o0;
            *(float4*)(pc + 4) = o1;
        }
    }
}

// ---------------------------------------------------------------- aggregation (CSR, no atomics)
// out[i] = dinv[i]^2 * h[i] + sum_{s in N(i)} dinv[i]*dinv[s]*h[s]
__global__ __launch_bounds__(256) void agg_kernel(const float* __restrict__ h,
                                                  const float* __restrict__ dinv,
                                                  const int* __restrict__ offsets,
                                                  const int* __restrict__ srcs,
                                                  float* __restrict__ out, int Nn) {
    int node = blockIdx.x * 2 + (threadIdx.x >> 7);
    int f = threadIdx.x & 127;
    if (node >= Nn) return;
    float di = dinv[node];
    float acc = di * di * h[(size_t)node * FOUT + f];
    int beg = offsets[node], end = offsets[node + 1];
    for (int e = beg; e < end; ++e) {
        int s = srcs[e];
        float nrm = di * dinv[s];
        acc = fmaf(nrm, h[(size_t)s * FOUT + f], acc);
    }
    out[(size_t)node * FOUT + f] = acc;
}

// ---------------------------------------------------------------- BN stats (sum, sumsq per column)
__global__ __launch_bounds__(256) void bn_stats_kernel(const float* __restrict__ x,
                                                       float* __restrict__ sum,
                                                       float* __restrict__ sumsq, int Nn) {
    const int T = gridDim.x * 256;  // multiple of 128
    int tid = blockIdx.x * 256 + threadIdx.x;
    float s1 = 0.f, s2 = 0.f;
    for (size_t i = tid; i < (size_t)Nn * FOUT; i += T) {
        float v = x[i];
        s1 += v;
        s2 += v * v;
    }
    __shared__ float sh1[256], sh2[256];
    sh1[threadIdx.x] = s1;
    sh2[threadIdx.x] = s2;
    __syncthreads();
    if (threadIdx.x < 128) {
        s1 = sh1[threadIdx.x] + sh1[threadIdx.x + 128];
        s2 = sh2[threadIdx.x] + sh2[threadIdx.x + 128];
        int f = (blockIdx.x * 256 + threadIdx.x) & 127;
        atomicAdd(&sum[f], s1);
        atomicAdd(&sumsq[f], s2);
    }
}

// ---------------------------------------------------------------- BN apply + leaky relu (in place)
__global__ __launch_bounds__(256) void bn_apply_kernel(float* __restrict__ x,
                                                       const float* __restrict__ sum,
                                                       const float* __restrict__ sumsq,
                                                       const float* __restrict__ gamma,
                                                       const float* __restrict__ beta, int Nn) {
    size_t i = (size_t)blockIdx.x * 256 + threadIdx.x;
    if (i >= (size_t)Nn * FOUT) return;
    int f = (int)(i & 127);
    const float invN = 1.0f / (float)NODES;
    float mu  = sum[f] * invN;
    float var = sumsq[f] * invN - mu * mu;
    float sc  = gamma[f] * rsqrtf(var + EPS);
    float v   = (x[i] - mu) * sc + beta[f];
    x[i] = (v >= 0.f) ? v : SLOPE * v;
}

// ================================================================ launch
extern "C" void kernel_launch(void* const* d_in, const int* in_sizes, int n_in,
                              void* d_out, int out_size, void* d_ws, size_t ws_size,
                              hipStream_t stream) {
    const float* x  = (const float*)d_in[0];
    const int*   ei = (const int*)d_in[1];
    const float* W1 = (const float*)d_in[2];
    const float* b1 = (const float*)d_in[3];
    const float* W2 = (const float*)d_in[4];
    const float* b2 = (const float*)d_in[5];
    const float* g1 = (const float*)d_in[6];
    const float* be1 = (const float*)d_in[7];
    const float* g2 = (const float*)d_in[8];
    const float* be2 = (const float*)d_in[9];
    float* out = (float*)d_out;

    const int E = in_sizes[1] / 2;
    const int* erow = ei;
    const int* ecol = ei + E;

    // ---- workspace layout
    float* bufA     = (float*)d_ws;            // 6,400,000 f
    float* dinv     = bufA + (size_t)NODES * FOUT;  // 50,000 f
    int*   deg      = (int*)(dinv + NODES);    // 50,000 i   } zero region start
    int*   cursor   = deg + NODES;             // 50,000 i
    float* colsumA  = (float*)(cursor + NODES);  // 128
    float* colsqA   = colsumA + 128;             // 128
    float* colsumB  = colsqA + 128;              // 128
    float* colsqB   = colsumB + 128;             // 128        } zero region end
    int*   offsets  = (int*)(colsqB + 128);    // 50,001 i
    int*   srcs     = offsets + (NODES + 1);   // E i

    size_t zero_bytes = (size_t)(2 * NODES) * sizeof(int) + 4 * 128 * sizeof(float);
    hipMemsetAsync(deg, 0, zero_bytes, stream);

    int egrid = (E + 255) / 256;
    deg_kernel<<<egrid, 256, 0, stream>>>(ecol, E, deg);
    scan_kernel<<<1, 1024, 0, stream>>>(deg, offsets, NODES);
    dinv_kernel<<<(NODES + 255) / 256, 256, 0, stream>>>(deg, dinv, NODES);
    fill_kernel<<<egrid, 256, 0, stream>>>(erow, ecol, E, offsets, cursor, srcs);

    const int mg = (NODES + 127) / 128;           // 391 GEMM blocks
    const int ag = (NODES + 1) / 2;               // 25000 agg blocks
    const int eg = ((size_t)NODES * FOUT + 255) / 256;  // 25000 elementwise blocks

    // ---- layer 1
    gemm_bias_kernel<FIN><<<mg, 256, 0, stream>>>(x, W1, b1, bufA, NODES);
    agg_kernel<<<ag, 256, 0, stream>>>(bufA, dinv, offsets, srcs, out, NODES);
    bn_stats_kernel<<<256, 256, 0, stream>>>(out, colsumA, colsqA, NODES);
    bn_apply_kernel<<<eg, 256, 0, stream>>>(out, colsumA, colsqA, g1, be1, NODES);

    // ---- layer 2
    gemm_bias_kernel<FOUT><<<mg, 256, 0, stream>>>(out, W2, b2, bufA, NODES);
    agg_kernel<<<ag, 256, 0, stream>>>(bufA, dinv, offsets, srcs, out, NODES);
    bn_stats_kernel<<<256, 256, 0, stream>>>(out, colsumB, colsqB, NODES);
    bn_apply_kernel<<<eg, 256, 0, stream>>>(out, colsumB, colsqB, g2, be2, NODES);
}

// Round 4
// 500.799 us; speedup vs baseline: 1.2624x; 1.2624x over previous
//
#include <hip/hip_runtime.h>

#define NODES 50000
#define FIN   256
#define FOUT  128
#define EPS   1e-5f
#define SLOPE 0.1f

// ---------------------------------------------------------------- degree count
__global__ void deg_kernel(const int* __restrict__ col, int E, int* __restrict__ deg) {
    int e = blockIdx.x * 256 + threadIdx.x;
    if (e < E) atomicAdd(&deg[col[e]], 1);
}

// ------------------------------------------------- exclusive scan (one block)
__global__ __launch_bounds__(1024) void scan_kernel(const int* __restrict__ deg,
                                                    int* __restrict__ offsets, int Nn) {
    __shared__ int sh[1024];
    const int t = threadIdx.x;
    const int C = (Nn + 1023) / 1024;
    const int start = t * C;
    int s = 0;
    for (int j = 0; j < C; ++j) {
        int i = start + j;
        if (i < Nn) s += deg[i];
    }
    sh[t] = s;
    __syncthreads();
    for (int off = 1; off < 1024; off <<= 1) {
        int v = (t >= off) ? sh[t - off] : 0;
        __syncthreads();
        sh[t] += v;
        __syncthreads();
    }
    int run = sh[t] - s;  // exclusive prefix of this thread's chunk
    for (int j = 0; j < C; ++j) {
        int i = start + j;
        if (i < Nn) { offsets[i] = run; run += deg[i]; }
    }
    if (t == 1023) offsets[Nn] = sh[1023];
}

// ---------------------------------------------------------------- dinv = (deg+1)^-1/2
__global__ void dinv_kernel(const int* __restrict__ deg, float* __restrict__ dinv, int Nn) {
    int i = blockIdx.x * 256 + threadIdx.x;
    if (i < Nn) dinv[i] = rsqrtf((float)(deg[i] + 1));
}

// ---------------------------------------------------------------- CSR fill (counting sort)
__global__ void fill_kernel(const int* __restrict__ row, const int* __restrict__ col, int E,
                            const int* __restrict__ offsets, int* __restrict__ cursor,
                            int* __restrict__ srcs) {
    int e = blockIdx.x * 256 + threadIdx.x;
    if (e < E) {
        int c = col[e];
        int p = offsets[c] + atomicAdd(&cursor[c], 1);
        srcs[p] = row[e];
    }
}

// ---------------------------------------------------------------- fp32 GEMM + bias
// C[M,128] = A[M,K] @ B[K,128] + bias ; BM=128, BN=128, BK=16, 8x8 microtile
template <int K>
__global__ __launch_bounds__(256) void gemm_bias_kernel(const float* __restrict__ A,
                                                        const float* __restrict__ B,
                                                        const float* __restrict__ bias,
                                                        float* __restrict__ C, int M) {
    __shared__ float Ast[16][132];  // [k][m], padded
    __shared__ float Bs[16][132];   // [k][n], padded
    const int tid = threadIdx.x;
    const int tx = tid & 15;
    const int ty = tid >> 4;
    const int m0 = blockIdx.x * 128;

    float acc[8][8];
#pragma unroll
    for (int i = 0; i < 8; ++i)
#pragma unroll
        for (int j = 0; j < 8; ++j) acc[i][j] = 0.f;

    const int ar   = tid >> 1;
    const int akc  = (tid & 1) * 8;
    const int arow = m0 + ar;
    const int bkr  = tid >> 4;
    const int bnc  = (tid & 15) * 8;

    for (int k0 = 0; k0 < K; k0 += 16) {
        float4 a0, a1;
        if (arow < M) {
            const float* p = A + (size_t)arow * K + k0 + akc;
            a0 = *(const float4*)p;
            a1 = *(const float4*)(p + 4);
        } else {
            a0 = make_float4(0.f, 0.f, 0.f, 0.f);
            a1 = a0;
        }
        Ast[akc + 0][ar] = a0.x; Ast[akc + 1][ar] = a0.y;
        Ast[akc + 2][ar] = a0.z; Ast[akc + 3][ar] = a0.w;
        Ast[akc + 4][ar] = a1.x; Ast[akc + 5][ar] = a1.y;
        Ast[akc + 6][ar] = a1.z; Ast[akc + 7][ar] = a1.w;

        const float* pb = B + (size_t)(k0 + bkr) * FOUT + bnc;
        float4 b0 = *(const float4*)pb;
        float4 b1 = *(const float4*)(pb + 4);
        *(float4*)&Bs[bkr][bnc]     = b0;
        *(float4*)&Bs[bkr][bnc + 4] = b1;

        __syncthreads();
#pragma unroll
        for (int kk = 0; kk < 16; ++kk) {
            float a[8], b[8];
            *(float4*)&a[0] = *(const float4*)&Ast[kk][ty * 8];
            *(float4*)&a[4] = *(const float4*)&Ast[kk][ty * 8 + 4];
            *(float4*)&b[0] = *(const float4*)&Bs[kk][tx * 8];
            *(float4*)&b[4] = *(const float4*)&Bs[kk][tx * 8 + 4];
#pragma unroll
            for (int i = 0; i < 8; ++i)
#pragma unroll
                for (int j = 0; j < 8; ++j) acc[i][j] = fmaf(a[i], b[j], acc[i][j]);
        }
        __syncthreads();
    }

    float bv[8];
#pragma unroll
    for (int j = 0; j < 8; ++j) bv[j] = bias[tx * 8 + j];
#pragma unroll
    for (int i = 0; i < 8; ++i) {
        int r = m0 + ty * 8 + i;
        if (r < M) {
            float4 o0, o1;
            o0.x = acc[i][0] + bv[0]; o0.y = acc[i][1] + bv[1];
            o0.z = acc[i][2] + bv[2]; o0.w = acc[i][3] + bv[3];
            o1.x = acc[i][4] + bv[4]; o1.y = acc[i][5] + bv[5];
            o1.z = acc[i][6] + bv[6]; o1.w = acc[i][7] + bv[7];
            float* pc = C + (size_t)r * FOUT + tx * 8;
            *(float4*)pc       = o0;
            *(float4*)(pc + 4) = o1;
        }
    }
}

// ---------------------------------------------------------------- aggregation (CSR, no atomics)
// out[i] = dinv[i]^2 * h[i] + sum_{s in N(i)} dinv[i]*dinv[s]*h[s]
// One node per 32-lane half-wave (32 x float4 = 128 feats), edge loop unrolled
// x4 with independent accumulators for memory-level parallelism.
__global__ __launch_bounds__(256) void agg_kernel(const float* __restrict__ h,
                                                  const float* __restrict__ dinv,
                                                  const int* __restrict__ offsets,
                                                  const int* __restrict__ srcs,
                                                  float* __restrict__ out, int Nn) {
    const int sub  = threadIdx.x >> 5;  // 0..7 half-wave id
    const int lane = threadIdx.x & 31;
    int node = blockIdx.x * 8 + sub;
    if (node >= Nn) return;
    const float4* __restrict__ h4 = (const float4*)h;  // 32 float4 per row
    float di = dinv[node];
    float4 hv = h4[(size_t)node * 32 + lane];
    float sw = di * di;
    float4 a0, a1, a2, a3;
    a0.x = sw * hv.x; a0.y = sw * hv.y; a0.z = sw * hv.z; a0.w = sw * hv.w;
    a1 = make_float4(0.f, 0.f, 0.f, 0.f);
    a2 = a1;
    a3 = a1;
    int beg = offsets[node], end = offsets[node + 1];
    int e = beg;
    for (; e + 4 <= end; e += 4) {
        int i0 = srcs[e], i1 = srcs[e + 1], i2 = srcs[e + 2], i3 = srcs[e + 3];
        float n0 = di * dinv[i0], n1 = di * dinv[i1];
        float n2 = di * dinv[i2], n3 = di * dinv[i3];
        float4 v0 = h4[(size_t)i0 * 32 + lane];
        float4 v1 = h4[(size_t)i1 * 32 + lane];
        float4 v2 = h4[(size_t)i2 * 32 + lane];
        float4 v3 = h4[(size_t)i3 * 32 + lane];
        a0.x = fmaf(n0, v0.x, a0.x); a0.y = fmaf(n0, v0.y, a0.y);
        a0.z = fmaf(n0, v0.z, a0.z); a0.w = fmaf(n0, v0.w, a0.w);
        a1.x = fmaf(n1, v1.x, a1.x); a1.y = fmaf(n1, v1.y, a1.y);
        a1.z = fmaf(n1, v1.z, a1.z); a1.w = fmaf(n1, v1.w, a1.w);
        a2.x = fmaf(n2, v2.x, a2.x); a2.y = fmaf(n2, v2.y, a2.y);
        a2.z = fmaf(n2, v2.z, a2.z); a2.w = fmaf(n2, v2.w, a2.w);
        a3.x = fmaf(n3, v3.x, a3.x); a3.y = fmaf(n3, v3.y, a3.y);
        a3.z = fmaf(n3, v3.z, a3.z); a3.w = fmaf(n3, v3.w, a3.w);
    }
    for (; e < end; ++e) {
        int s = srcs[e];
        float n = di * dinv[s];
        float4 v = h4[(size_t)s * 32 + lane];
        a0.x = fmaf(n, v.x, a0.x); a0.y = fmaf(n, v.y, a0.y);
        a0.z = fmaf(n, v.z, a0.z); a0.w = fmaf(n, v.w, a0.w);
    }
    a0.x += a1.x + a2.x + a3.x;
    a0.y += a1.y + a2.y + a3.y;
    a0.z += a1.z + a2.z + a3.z;
    a0.w += a1.w + a2.w + a3.w;
    float4* __restrict__ o4 = (float4*)out;
    o4[(size_t)node * 32 + lane] = a0;
}

// ---------------------------------------------------------------- BN stats (sum, sumsq per column)
__global__ __launch_bounds__(256) void bn_stats_kernel(const float* __restrict__ x,
                                                       float* __restrict__ sum,
                                                       float* __restrict__ sumsq, int Nn) {
    const int T = gridDim.x * 256;  // multiple of 128
    int tid = blockIdx.x * 256 + threadIdx.x;
    float s1 = 0.f, s2 = 0.f;
    for (size_t i = tid; i < (size_t)Nn * FOUT; i += T) {
        float v = x[i];
        s1 += v;
        s2 += v * v;
    }
    __shared__ float sh1[256], sh2[256];
    sh1[threadIdx.x] = s1;
    sh2[threadIdx.x] = s2;
    __syncthreads();
    if (threadIdx.x < 128) {
        s1 = sh1[threadIdx.x] + sh1[threadIdx.x + 128];
        s2 = sh2[threadIdx.x] + sh2[threadIdx.x + 128];
        int f = (blockIdx.x * 256 + threadIdx.x) & 127;
        atomicAdd(&sum[f], s1);
        atomicAdd(&sumsq[f], s2);
    }
}

// ---------------------------------------------------------------- BN apply + leaky relu (in place)
__global__ __launch_bounds__(256) void bn_apply_kernel(float* __restrict__ x,
                                                       const float* __restrict__ sum,
                                                       const float* __restrict__ sumsq,
                                                       const float* __restrict__ gamma,
                                                       const float* __restrict__ beta, int Nn) {
    size_t i = (size_t)blockIdx.x * 256 + threadIdx.x;
    if (i >= (size_t)Nn * FOUT) return;
    int f = (int)(i & 127);
    const float invN = 1.0f / (float)NODES;
    float mu  = sum[f] * invN;
    float var = sumsq[f] * invN - mu * mu;
    float sc  = gamma[f] * rsqrtf(var + EPS);
    float v   = (x[i] - mu) * sc + beta[f];
    x[i] = (v >= 0.f) ? v : SLOPE * v;
}

// ================================================================ launch
extern "C" void kernel_launch(void* const* d_in, const int* in_sizes, int n_in,
                              void* d_out, int out_size, void* d_ws, size_t ws_size,
                              hipStream_t stream) {
    const float* x  = (const float*)d_in[0];
    const int*   ei = (const int*)d_in[1];
    const float* W1 = (const float*)d_in[2];
    const float* b1 = (const float*)d_in[3];
    const float* W2 = (const float*)d_in[4];
    const float* b2 = (const float*)d_in[5];
    const float* g1 = (const float*)d_in[6];
    const float* be1 = (const float*)d_in[7];
    const float* g2 = (const float*)d_in[8];
    const float* be2 = (const float*)d_in[9];
    float* out = (float*)d_out;

    const int E = in_sizes[1] / 2;
    const int* erow = ei;
    const int* ecol = ei + E;

    // ---- workspace layout
    float* bufA     = (float*)d_ws;            // 6,400,000 f
    float* dinv     = bufA + (size_t)NODES * FOUT;  // 50,000 f
    int*   deg      = (int*)(dinv + NODES);    // 50,000 i   } zero region start
    int*   cursor   = deg + NODES;             // 50,000 i
    float* colsumA  = (float*)(cursor + NODES);  // 128
    float* colsqA   = colsumA + 128;             // 128
    float* colsumB  = colsqA + 128;              // 128
    float* colsqB   = colsumB + 128;             // 128        } zero region end
    int*   offsets  = (int*)(colsqB + 128);    // 50,001 i
    int*   srcs     = offsets + (NODES + 1);   // E i

    size_t zero_bytes = (size_t)(2 * NODES) * sizeof(int) + 4 * 128 * sizeof(float);
    hipMemsetAsync(deg, 0, zero_bytes, stream);

    int egrid = (E + 255) / 256;
    deg_kernel<<<egrid, 256, 0, stream>>>(ecol, E, deg);
    scan_kernel<<<1, 1024, 0, stream>>>(deg, offsets, NODES);
    dinv_kernel<<<(NODES + 255) / 256, 256, 0, stream>>>(deg, dinv, NODES);
    fill_kernel<<<egrid, 256, 0, stream>>>(erow, ecol, E, offsets, cursor, srcs);

    const int mg = (NODES + 127) / 128;           // 391 GEMM blocks
    const int ag = (NODES + 7) / 8;               // 6250 agg blocks
    const int eg = ((size_t)NODES * FOUT + 255) / 256;  // 25000 elementwise blocks

    // ---- layer 1
    gemm_bias_kernel<FIN><<<mg, 256, 0, stream>>>(x, W1, b1, bufA, NODES);
    agg_kernel<<<ag, 256, 0, stream>>>(bufA, dinv, offsets, srcs, out, NODES);
    bn_stats_kernel<<<256, 256, 0, stream>>>(out, colsumA, colsqA, NODES);
    bn_apply_kernel<<<eg, 256, 0, stream>>>(out, colsumA, colsqA, g1, be1, NODES);

    // ---- layer 2
    gemm_bias_kernel<FOUT><<<mg, 256, 0, stream>>>(out, W2, b2, bufA, NODES);
    agg_kernel<<<ag, 256, 0, stream>>>(bufA, dinv, offsets, srcs, out, NODES);
    bn_stats_kernel<<<256, 256, 0, stream>>>(out, colsumB, colsqB, NODES);
    bn_apply_kernel<<<eg, 256, 0, stream>>>(out, colsumB, colsqB, g2, be2, NODES);
}

// Round 9
// 380.681 us; speedup vs baseline: 1.6608x; 1.3155x over previous
//
#include <hip/hip_runtime.h>

#define NODES 50000
#define FIN   256
#define FOUT  128
#define EPS   1e-5f
#define SLOPE 0.1f
#define SCAN_CHUNK 512
#define SCAN_NB ((NODES + SCAN_CHUNK - 1) / SCAN_CHUNK)  // 98

typedef __attribute__((ext_vector_type(8))) short short8_t;   // 8 bf16 = 4 VGPRs
typedef __attribute__((ext_vector_type(4))) float f32x4_t;    // MFMA accumulator

// fp32 -> bf16 bits, round-to-nearest-even
__device__ __forceinline__ ushort f2bf(float f) {
    union { float f; unsigned u; } v; v.f = f;
    return (ushort)((v.u + 0x7FFFu + ((v.u >> 16) & 1u)) >> 16);
}

// ---------------------------------------------------------------- degree count
__global__ void deg_kernel(const int* __restrict__ col, int E, int* __restrict__ deg) {
    int e = blockIdx.x * 256 + threadIdx.x;
    if (e < E) atomicAdd(&deg[col[e]], 1);
}

// ------------------------------------------------- hierarchical scan, pass 1
__global__ __launch_bounds__(256) void scan1_kernel(const int* __restrict__ deg,
                                                    int* __restrict__ partials, int Nn) {
    const int t = threadIdx.x;
    const int i0 = blockIdx.x * SCAN_CHUNK + 2 * t;
    int e0 = (i0 < Nn) ? deg[i0] : 0;
    int e1 = (i0 + 1 < Nn) ? deg[i0 + 1] : 0;
    __shared__ int sh[256];
    sh[t] = e0 + e1;
    __syncthreads();
    for (int off = 128; off > 0; off >>= 1) {
        if (t < off) sh[t] += sh[t + off];
        __syncthreads();
    }
    if (t == 0) partials[blockIdx.x] = sh[0];
}

// ------------------------------------------------- pass 2: scan partials
__global__ __launch_bounds__(128) void scan2_kernel(const int* __restrict__ partials,
                                                    int* __restrict__ partials_pre,
                                                    int* __restrict__ offN, int total) {
    __shared__ int sh[128];
    const int t = threadIdx.x;
    int v = (t < SCAN_NB) ? partials[t] : 0;
    sh[t] = v;
    __syncthreads();
    for (int off = 1; off < 128; off <<= 1) {
        int u = (t >= off) ? sh[t - off] : 0;
        __syncthreads();
        sh[t] += u;
        __syncthreads();
    }
    if (t < SCAN_NB) partials_pre[t] = sh[t] - v;
    if (t == 0) *offN = total;
}

// ------------------------------------------------- pass 3: in-block scan + prefix
__global__ __launch_bounds__(256) void scan3_kernel(const int* __restrict__ deg,
                                                    const int* __restrict__ partials_pre,
                                                    int* __restrict__ offsets, int Nn) {
    const int t = threadIdx.x;
    const int i0 = blockIdx.x * SCAN_CHUNK + 2 * t;
    int e0 = (i0 < Nn) ? deg[i0] : 0;
    int e1 = (i0 + 1 < Nn) ? deg[i0 + 1] : 0;
    int s = e0 + e1;
    __shared__ int sh[256];
    sh[t] = s;
    __syncthreads();
    for (int off = 1; off < 256; off <<= 1) {
        int u = (t >= off) ? sh[t - off] : 0;
        __syncthreads();
        sh[t] += u;
        __syncthreads();
    }
    int ex = sh[t] - s + partials_pre[blockIdx.x];
    if (i0 < Nn) offsets[i0] = ex;
    if (i0 + 1 < Nn) offsets[i0 + 1] = ex + e0;
}

// ---------------------------------------------------------------- dinv = (deg+1)^-1/2
__global__ void dinv_kernel(const int* __restrict__ deg, float* __restrict__ dinv, int Nn) {
    int i = blockIdx.x * 256 + threadIdx.x;
    if (i < Nn) dinv[i] = rsqrtf((float)(deg[i] + 1));
}

// ---------------------------------------------------------------- CSR fill
__global__ void fill_kernel(const int* __restrict__ row, const int* __restrict__ col, int E,
                            const int* __restrict__ offsets, int* __restrict__ cursor,
                            int* __restrict__ srcs) {
    int e = blockIdx.x * 256 + threadIdx.x;
    if (e < E) {
        int c = col[e];
        int p = offsets[c] + atomicAdd(&cursor[c], 1);
        srcs[p] = row[e];
    }
}

// ---------------------------------------------------------------- W -> bf16 transposed
// W[k][128] fp32  ->  Bt[n][K] bf16 bits. idx = k*128 + n (coalesced reads).
template <int K>
__global__ __launch_bounds__(256) void wcvt_kernel(const float* __restrict__ W,
                                                   ushort* __restrict__ Bt) {
    int idx = blockIdx.x * 256 + threadIdx.x;
    int k = idx >> 7, n = idx & 127;
    if (k < K) Bt[n * K + k] = f2bf(W[idx]);
}

// ---------------------------------------------------------------- bf16 MFMA GEMM + bias
// C[M,128] = A[M,K] @ B[K,128] + bias.  A fp32 (converted in staging),
// Bt = B^T in bf16 [128][K].  BM=128, BN=128, BK=32; 4 waves, each wave
// 2 m-tiles x 8 n-tiles of mfma_f32_16x16x32_bf16.
// Verified fragment mapping (guide §3, m89/m91):
//   A: lane l -> A[l&15][(l>>4)*8+j] ; B: lane l -> B[(l>>4)*8+j][l&15]
//   D: lane l, reg r -> C[(l>>4)*4+r][l&15]
template <int K>
__global__ __launch_bounds__(256) void gemm_mfma_kernel(const float* __restrict__ A,
                                                        const ushort* __restrict__ Bt,
                                                        const float* __restrict__ bias,
                                                        float* __restrict__ C, int M) {
    __shared__ ushort As[128 * 40];  // [row][k] bf16, row stride 40 (pad)
    __shared__ ushort Bs[128 * 40];  // [n][k]   bf16, row stride 40 (pad)
    const int tid  = threadIdx.x;
    const int lane = tid & 63;
    const int w    = tid >> 6;       // wave 0..3 -> rows w*32..w*32+31
    const int m0   = blockIdx.x * 128;
    const int ml   = lane & 15;
    const int kg   = lane >> 4;      // k-group 0..3

    f32x4_t acc[2][8];
    const f32x4_t zero = {0.f, 0.f, 0.f, 0.f};
#pragma unroll
    for (int a = 0; a < 2; ++a)
#pragma unroll
        for (int b = 0; b < 8; ++b) acc[a][b] = zero;

    const int sr = tid >> 1;         // A-stage row 0..127
    const int sh = tid & 1;          // A-stage half (16 floats = 64 B)
    const bool aok = (m0 + sr) < M;
    const float* ap = A + (size_t)(m0 + sr) * K + sh * 16;

    for (int k0 = 0; k0 < K; k0 += 32) {
        __syncthreads();
        // ---- stage A tile [128][32] fp32 -> bf16 (coalesced 64 B / thread)
        float4 v0, v1, v2, v3;
        if (aok) {
            const float* p = ap + k0;
            v0 = *(const float4*)(p + 0);  v1 = *(const float4*)(p + 4);
            v2 = *(const float4*)(p + 8);  v3 = *(const float4*)(p + 12);
        } else {
            v0 = make_float4(0.f, 0.f, 0.f, 0.f); v1 = v0; v2 = v0; v3 = v0;
        }
        short8_t oa, ob;
        oa[0] = (short)f2bf(v0.x); oa[1] = (short)f2bf(v0.y);
        oa[2] = (short)f2bf(v0.z); oa[3] = (short)f2bf(v0.w);
        oa[4] = (short)f2bf(v1.x); oa[5] = (short)f2bf(v1.y);
        oa[6] = (short)f2bf(v1.z); oa[7] = (short)f2bf(v1.w);
        ob[0] = (short)f2bf(v2.x); ob[1] = (short)f2bf(v2.y);
        ob[2] = (short)f2bf(v2.z); ob[3] = (short)f2bf(v2.w);
        ob[4] = (short)f2bf(v3.x); ob[5] = (short)f2bf(v3.y);
        ob[6] = (short)f2bf(v3.z); ob[7] = (short)f2bf(v3.w);
        *(short8_t*)&As[sr * 40 + sh * 16]     = oa;
        *(short8_t*)&As[sr * 40 + sh * 16 + 8] = ob;
        // ---- stage B tile [128][32] (already bf16 in global Bt)
#pragma unroll
        for (int cc = 0; cc < 2; ++cc) {
            int c  = tid + cc * 256;       // 0..511 chunks of 8 shorts
            int bn = c >> 2;
            int bs = (c & 3) * 8;
            *(short8_t*)&Bs[bn * 40 + bs] = *(const short8_t*)&Bt[bn * K + k0 + bs];
        }
        __syncthreads();
        // ---- 16 MFMA
        short8_t af0 = *(const short8_t*)&As[(w * 32 + ml) * 40 + kg * 8];
        short8_t af1 = *(const short8_t*)&As[(w * 32 + 16 + ml) * 40 + kg * 8];
#pragma unroll
        for (int nt = 0; nt < 8; ++nt) {
            short8_t bf = *(const short8_t*)&Bs[(nt * 16 + ml) * 40 + kg * 8];
            acc[0][nt] = __builtin_amdgcn_mfma_f32_16x16x32_bf16(af0, bf, acc[0][nt], 0, 0, 0);
            acc[1][nt] = __builtin_amdgcn_mfma_f32_16x16x32_bf16(af1, bf, acc[1][nt], 0, 0, 0);
        }
    }
    // ---- epilogue: bias + store
#pragma unroll
    for (int nt = 0; nt < 8; ++nt) {
        float bv = bias[nt * 16 + ml];
#pragma unroll
        for (int mt = 0; mt < 2; ++mt) {
            int mr0 = m0 + w * 32 + mt * 16 + kg * 4;
#pragma unroll
            for (int rr = 0; rr < 4; ++rr) {
                int mr = mr0 + rr;
                if (mr < M) C[(size_t)mr * FOUT + nt * 16 + ml] = acc[mt][nt][rr] + bv;
            }
        }
    }
}

// ---------------------------------------------------------------- aggregation (CSR, no atomics)
__global__ __launch_bounds__(256) void agg_kernel(const float* __restrict__ h,
                                                  const float* __restrict__ dinv,
                                                  const int* __restrict__ offsets,
                                                  const int* __restrict__ srcs,
                                                  float* __restrict__ out, int Nn) {
    const int sub  = threadIdx.x >> 5;
    const int lane = threadIdx.x & 31;
    int node = blockIdx.x * 8 + sub;
    if (node >= Nn) return;
    const float4* __restrict__ h4 = (const float4*)h;
    float di = dinv[node];
    float4 hv = h4[(size_t)node * 32 + lane];
    float sw = di * di;
    float4 a0, a1, a2, a3;
    a0.x = sw * hv.x; a0.y = sw * hv.y; a0.z = sw * hv.z; a0.w = sw * hv.w;
    a1 = make_float4(0.f, 0.f, 0.f, 0.f);
    a2 = a1;
    a3 = a1;
    int beg = offsets[node], end = offsets[node + 1];
    int e = beg;
    for (; e + 4 <= end; e += 4) {
        int i0 = srcs[e], i1 = srcs[e + 1], i2 = srcs[e + 2], i3 = srcs[e + 3];
        float n0 = di * dinv[i0], n1 = di * dinv[i1];
        float n2 = di * dinv[i2], n3 = di * dinv[i3];
        float4 v0 = h4[(size_t)i0 * 32 + lane];
        float4 v1 = h4[(size_t)i1 * 32 + lane];
        float4 v2 = h4[(size_t)i2 * 32 + lane];
        float4 v3 = h4[(size_t)i3 * 32 + lane];
        a0.x = fmaf(n0, v0.x, a0.x); a0.y = fmaf(n0, v0.y, a0.y);
        a0.z = fmaf(n0, v0.z, a0.z); a0.w = fmaf(n0, v0.w, a0.w);
        a1.x = fmaf(n1, v1.x, a1.x); a1.y = fmaf(n1, v1.y, a1.y);
        a1.z = fmaf(n1, v1.z, a1.z); a1.w = fmaf(n1, v1.w, a1.w);
        a2.x = fmaf(n2, v2.x, a2.x); a2.y = fmaf(n2, v2.y, a2.y);
        a2.z = fmaf(n2, v2.z, a2.z); a2.w = fmaf(n2, v2.w, a2.w);
        a3.x = fmaf(n3, v3.x, a3.x); a3.y = fmaf(n3, v3.y, a3.y);
        a3.z = fmaf(n3, v3.z, a3.z); a3.w = fmaf(n3, v3.w, a3.w);
    }
    for (; e < end; ++e) {
        int s = srcs[e];
        float n = di * dinv[s];
        float4 v = h4[(size_t)s * 32 + lane];
        a0.x = fmaf(n, v.x, a0.x); a0.y = fmaf(n, v.y, a0.y);
        a0.z = fmaf(n, v.z, a0.z); a0.w = fmaf(n, v.w, a0.w);
    }
    a0.x += a1.x + a2.x + a3.x;
    a0.y += a1.y + a2.y + a3.y;
    a0.z += a1.z + a2.z + a3.z;
    a0.w += a1.w + a2.w + a3.w;
    float4* __restrict__ o4 = (float4*)out;
    o4[(size_t)node * 32 + lane] = a0;
}

// ---------------------------------------------------------------- BN stats
__global__ __launch_bounds__(256) void bn_stats_kernel(const float* __restrict__ x,
                                                       float* __restrict__ sum,
                                                       float* __restrict__ sumsq, int Nn) {
    const int T = gridDim.x * 256;
    int tid = blockIdx.x * 256 + threadIdx.x;
    float s1 = 0.f, s2 = 0.f;
    for (size_t i = tid; i < (size_t)Nn * FOUT; i += T) {
        float v = x[i];
        s1 += v;
        s2 += v * v;
    }
    __shared__ float sh1[256], sh2[256];
    sh1[threadIdx.x] = s1;
    sh2[threadIdx.x] = s2;
    __syncthreads();
    if (threadIdx.x < 128) {
        s1 = sh1[threadIdx.x] + sh1[threadIdx.x + 128];
        s2 = sh2[threadIdx.x] + sh2[threadIdx.x + 128];
        int f = (blockIdx.x * 256 + threadIdx.x) & 127;
        atomicAdd(&sum[f], s1);
        atomicAdd(&sumsq[f], s2);
    }
}

// ---------------------------------------------------------------- BN apply + leaky relu
__global__ __launch_bounds__(256) void bn_apply_kernel(float* __restrict__ x,
                                                       const float* __restrict__ sum,
                                                       const float* __restrict__ sumsq,
                                                       const float* __restrict__ gamma,
                                                       const float* __restrict__ beta, int Nn) {
    size_t i = (size_t)blockIdx.x * 256 + threadIdx.x;
    if (i >= (size_t)Nn * FOUT) return;
    int f = (int)(i & 127);
    const float invN = 1.0f / (float)NODES;
    float mu  = sum[f] * invN;
    float var = sumsq[f] * invN - mu * mu;
    float sc  = gamma[f] * rsqrtf(var + EPS);
    float v   = (x[i] - mu) * sc + beta[f];
    x[i] = (v >= 0.f) ? v : SLOPE * v;
}

// ================================================================ launch
extern "C" void kernel_launch(void* const* d_in, const int* in_sizes, int n_in,
                              void* d_out, int out_size, void* d_ws, size_t ws_size,
                              hipStream_t stream) {
    const float* x  = (const float*)d_in[0];
    const int*   ei = (const int*)d_in[1];
    const float* W1 = (const float*)d_in[2];
    const float* b1 = (const float*)d_in[3];
    const float* W2 = (const float*)d_in[4];
    const float* b2 = (const float*)d_in[5];
    const float* g1 = (const float*)d_in[6];
    const float* be1 = (const float*)d_in[7];
    const float* g2 = (const float*)d_in[8];
    const float* be2 = (const float*)d_in[9];
    float* out = (float*)d_out;

    const int E = in_sizes[1] / 2;
    const int* erow = ei;
    const int* ecol = ei + E;

    // ---- workspace layout
    float* bufA     = (float*)d_ws;                 // 6,400,000 f
    float* dinv     = bufA + (size_t)NODES * FOUT;  // 50,000 f
    int*   deg      = (int*)(dinv + NODES);         // 50,000 i   } zero region start
    int*   cursor   = deg + NODES;                  // 50,000 i  (reused as Bt after fill)
    float* colsumA  = (float*)(cursor + NODES);     // 128
    float* colsqA   = colsumA + 128;                // 128
    float* colsumB  = colsqA + 128;                 // 128
    float* colsqB   = colsumB + 128;                // 128        } zero region end
    int*   offsets  = (int*)(colsqB + 128);         // 50,001 i
    int*   srcs     = offsets + (NODES + 1);        // E i
    int*   partials = srcs + E;                     // 98 i
    int*   partpre  = partials + SCAN_NB;           // 98 i
    // Bt1/Bt2 alias the cursor region (200 KB >= 96 KB needed; cursor is dead
    // after fill_kernel; wcvt kernels launch after fill). 16-B aligned: cursor
    // byte offset = 6,500,000*4.
    ushort* Bt1 = (ushort*)cursor;                  // 128*256 bf16
    ushort* Bt2 = Bt1 + 128 * FIN;                  // 128*128 bf16

    size_t zero_bytes = (size_t)(2 * NODES) * sizeof(int) + 4 * 128 * sizeof(float);
    hipMemsetAsync(deg, 0, zero_bytes, stream);

    int egrid = (E + 255) / 256;
    deg_kernel<<<egrid, 256, 0, stream>>>(ecol, E, deg);
    scan1_kernel<<<SCAN_NB, 256, 0, stream>>>(deg, partials, NODES);
    scan2_kernel<<<1, 128, 0, stream>>>(partials, partpre, &offsets[NODES], E);
    scan3_kernel<<<SCAN_NB, 256, 0, stream>>>(deg, partpre, offsets, NODES);
    dinv_kernel<<<(NODES + 255) / 256, 256, 0, stream>>>(deg, dinv, NODES);
    fill_kernel<<<egrid, 256, 0, stream>>>(erow, ecol, E, offsets, cursor, srcs);
    // cursor dead from here on; convert weights into its storage
    wcvt_kernel<FIN><<<(128 * FIN) / 256, 256, 0, stream>>>(W1, Bt1);
    wcvt_kernel<FOUT><<<(128 * FOUT) / 256, 256, 0, stream>>>(W2, Bt2);

    const int mg = (NODES + 127) / 128;                 // 391 GEMM blocks
    const int ag = (NODES + 7) / 8;                     // 6250 agg blocks
    const int eg = ((size_t)NODES * FOUT + 255) / 256;  // 25000 elementwise blocks

    // ---- layer 1
    gemm_mfma_kernel<FIN><<<mg, 256, 0, stream>>>(x, Bt1, b1, bufA, NODES);
    agg_kernel<<<ag, 256, 0, stream>>>(bufA, dinv, offsets, srcs, out, NODES);
    bn_stats_kernel<<<256, 256, 0, stream>>>(out, colsumA, colsqA, NODES);
    bn_apply_kernel<<<eg, 256, 0, stream>>>(out, colsumA, colsqA, g1, be1, NODES);

    // ---- layer 2
    gemm_mfma_kernel<FOUT><<<mg, 256, 0, stream>>>(out, Bt2, b2, bufA, NODES);
    agg_kernel<<<ag, 256, 0, stream>>>(bufA, dinv, offsets, srcs, out, NODES);
    bn_stats_kernel<<<256, 256, 0, stream>>>(out, colsumB, colsqB, NODES);
    bn_apply_kernel<<<eg, 256, 0, stream>>>(out, colsumB, colsqB, g2, be2, NODES);
}

// Round 11
// 340.014 us; speedup vs baseline: 1.8594x; 1.1196x over previous
//
#include <hip/hip_runtime.h>

#define NODES 50000
#define FIN   256
#define FOUT  128
#define EPS   1e-5f
#define SLOPE 0.1f
#define SCAN_CHUNK 512
#define SCAN_NB ((NODES + SCAN_CHUNK - 1) / SCAN_CHUNK)  // 98

typedef __attribute__((ext_vector_type(8))) short short8_t;   // 8 bf16 = 4 VGPRs
typedef __attribute__((ext_vector_type(4))) float f32x4_t;    // MFMA accumulator

// fp32 -> bf16 bits, round-to-nearest-even
__device__ __forceinline__ ushort f2bf(float f) {
    union { float f; unsigned u; } v; v.f = f;
    return (ushort)((v.u + 0x7FFFu + ((v.u >> 16) & 1u)) >> 16);
}
// bf16 bits -> fp32
__device__ __forceinline__ float bf2f(ushort u) {
    union { unsigned x; float f; } v; v.x = ((unsigned)u) << 16; return v.f;
}

// ---------------------------------------------------------------- degree count
__global__ void deg_kernel(const int* __restrict__ col, int E, int* __restrict__ deg) {
    int e = blockIdx.x * 256 + threadIdx.x;
    if (e < E) atomicAdd(&deg[col[e]], 1);
}

// ------------------------------------------------- hierarchical scan, pass 1
__global__ __launch_bounds__(256) void scan1_kernel(const int* __restrict__ deg,
                                                    int* __restrict__ partials, int Nn) {
    const int t = threadIdx.x;
    const int i0 = blockIdx.x * SCAN_CHUNK + 2 * t;
    int e0 = (i0 < Nn) ? deg[i0] : 0;
    int e1 = (i0 + 1 < Nn) ? deg[i0 + 1] : 0;
    __shared__ int sh[256];
    sh[t] = e0 + e1;
    __syncthreads();
    for (int off = 128; off > 0; off >>= 1) {
        if (t < off) sh[t] += sh[t + off];
        __syncthreads();
    }
    if (t == 0) partials[blockIdx.x] = sh[0];
}

// ------------------------------------------------- pass 2: scan partials
__global__ __launch_bounds__(128) void scan2_kernel(const int* __restrict__ partials,
                                                    int* __restrict__ partials_pre,
                                                    int* __restrict__ offN, int total) {
    __shared__ int sh[128];
    const int t = threadIdx.x;
    int v = (t < SCAN_NB) ? partials[t] : 0;
    sh[t] = v;
    __syncthreads();
    for (int off = 1; off < 128; off <<= 1) {
        int u = (t >= off) ? sh[t - off] : 0;
        __syncthreads();
        sh[t] += u;
        __syncthreads();
    }
    if (t < SCAN_NB) partials_pre[t] = sh[t] - v;
    if (t == 0) *offN = total;
}

// ------------------------------------------------- pass 3: in-block scan + prefix (+ fused dinv)
__global__ __launch_bounds__(256) void scan3_kernel(const int* __restrict__ deg,
                                                    const int* __restrict__ partials_pre,
                                                    int* __restrict__ offsets,
                                                    float* __restrict__ dinv, int Nn) {
    const int t = threadIdx.x;
    const int i0 = blockIdx.x * SCAN_CHUNK + 2 * t;
    int e0 = (i0 < Nn) ? deg[i0] : 0;
    int e1 = (i0 + 1 < Nn) ? deg[i0 + 1] : 0;
    int s = e0 + e1;
    __shared__ int sh[256];
    sh[t] = s;
    __syncthreads();
    for (int off = 1; off < 256; off <<= 1) {
        int u = (t >= off) ? sh[t - off] : 0;
        __syncthreads();
        sh[t] += u;
        __syncthreads();
    }
    int ex = sh[t] - s + partials_pre[blockIdx.x];
    if (i0 < Nn)     { offsets[i0] = ex;          dinv[i0] = rsqrtf((float)(e0 + 1)); }
    if (i0 + 1 < Nn) { offsets[i0 + 1] = ex + e0; dinv[i0 + 1] = rsqrtf((float)(e1 + 1)); }
}

// ---------------------------------------------------------------- CSR fill
__global__ void fill_kernel(const int* __restrict__ row, const int* __restrict__ col, int E,
                            const int* __restrict__ offsets, int* __restrict__ cursor,
                            int* __restrict__ srcs) {
    int e = blockIdx.x * 256 + threadIdx.x;
    if (e < E) {
        int c = col[e];
        int p = offsets[c] + atomicAdd(&cursor[c], 1);
        srcs[p] = row[e];
    }
}

// ---------------------------------------------------------------- W -> bf16 transposed
template <int K>
__global__ __launch_bounds__(256) void wcvt_kernel(const float* __restrict__ W,
                                                   ushort* __restrict__ Bt) {
    int idx = blockIdx.x * 256 + threadIdx.x;
    int k = idx >> 7, n = idx & 127;
    if (k < K) Bt[n * K + k] = f2bf(W[idx]);
}

// ---------------------------------------------------------------- BN finalize: stats -> scale/shift
__global__ void bn_finalize_kernel(const float* __restrict__ sum, const float* __restrict__ sumsq,
                                   const float* __restrict__ gamma, const float* __restrict__ beta,
                                   float* __restrict__ scale, float* __restrict__ shift) {
    int f = threadIdx.x;  // 128
    const float invN = 1.0f / (float)NODES;
    float mu  = sum[f] * invN;
    float var = sumsq[f] * invN - mu * mu;
    float sc  = gamma[f] * rsqrtf(var + EPS);
    scale[f] = sc;
    shift[f] = beta[f] - mu * sc;
}

// ---------------------------------------------------------------- bf16 MFMA GEMM + bias (+opt fused BN+LeakyReLU on A)
// C[M,128] (bf16) = act(A[M,K]) @ B[K,128] + bias, act = FUSE ? leakyrelu(A*scale+shift) : A.
// Bt = B^T bf16 [128][K]. BM=128, BN=128, BK=32; 4 waves x (2 m-tiles x 8 n-tiles) 16x16x32.
// Fragment mapping (HW-verified, guide §3 m89/m91):
//   A: lane l -> A[l&15][(l>>4)*8+j] ; B: lane l -> B[(l>>4)*8+j][l&15]
//   D: lane l, reg r -> C[(l>>4)*4+r][l&15]
template <int K, bool FUSE>
__global__ __launch_bounds__(256) void gemm_mfma_kernel(const float* __restrict__ A,
                                                        const ushort* __restrict__ Bt,
                                                        const float* __restrict__ bias,
                                                        const float* __restrict__ scale,
                                                        const float* __restrict__ shift,
                                                        ushort* __restrict__ C, int M) {
    __shared__ ushort As[128 * 40];  // [row][k] bf16, row stride 40 (pad)
    __shared__ ushort Bs[128 * 40];  // [n][k]   bf16, row stride 40 (pad)
    const int tid  = threadIdx.x;
    const int lane = tid & 63;
    const int w    = tid >> 6;
    const int m0   = blockIdx.x * 128;
    const int ml   = lane & 15;
    const int kg   = lane >> 4;

    f32x4_t acc[2][8];
    const f32x4_t zero = {0.f, 0.f, 0.f, 0.f};
#pragma unroll
    for (int a = 0; a < 2; ++a)
#pragma unroll
        for (int b = 0; b < 8; ++b) acc[a][b] = zero;

    const int sr = tid >> 1;
    const int sh = tid & 1;
    const bool aok = (m0 + sr) < M;
    const float* ap = A + (size_t)(m0 + sr) * K + sh * 16;

    for (int k0 = 0; k0 < K; k0 += 32) {
        __syncthreads();
        // ---- stage A tile [128][32] fp32 -> (BN+lrelu) -> bf16
        float vv[16];
        if (aok) {
            const float* p = ap + k0;
            *(float4*)&vv[0]  = *(const float4*)(p + 0);
            *(float4*)&vv[4]  = *(const float4*)(p + 4);
            *(float4*)&vv[8]  = *(const float4*)(p + 8);
            *(float4*)&vv[12] = *(const float4*)(p + 12);
            if (FUSE) {
                int kb = k0 + sh * 16;
#pragma unroll
                for (int j = 0; j < 16; ++j) {
                    float val = fmaf(vv[j], scale[kb + j], shift[kb + j]);
                    vv[j] = (val >= 0.f) ? val : SLOPE * val;
                }
            }
        } else {
#pragma unroll
            for (int j = 0; j < 16; ++j) vv[j] = 0.f;
        }
        short8_t oa, ob;
#pragma unroll
        for (int j = 0; j < 8; ++j) { oa[j] = (short)f2bf(vv[j]); ob[j] = (short)f2bf(vv[8 + j]); }
        *(short8_t*)&As[sr * 40 + sh * 16]     = oa;
        *(short8_t*)&As[sr * 40 + sh * 16 + 8] = ob;
        // ---- stage B tile [128][32]
#pragma unroll
        for (int cc = 0; cc < 2; ++cc) {
            int c  = tid + cc * 256;
            int bn = c >> 2;
            int bs = (c & 3) * 8;
            *(short8_t*)&Bs[bn * 40 + bs] = *(const short8_t*)&Bt[bn * K + k0 + bs];
        }
        __syncthreads();
        // ---- 16 MFMA
        short8_t af0 = *(const short8_t*)&As[(w * 32 + ml) * 40 + kg * 8];
        short8_t af1 = *(const short8_t*)&As[(w * 32 + 16 + ml) * 40 + kg * 8];
#pragma unroll
        for (int nt = 0; nt < 8; ++nt) {
            short8_t bf = *(const short8_t*)&Bs[(nt * 16 + ml) * 40 + kg * 8];
            acc[0][nt] = __builtin_amdgcn_mfma_f32_16x16x32_bf16(af0, bf, acc[0][nt], 0, 0, 0);
            acc[1][nt] = __builtin_amdgcn_mfma_f32_16x16x32_bf16(af1, bf, acc[1][nt], 0, 0, 0);
        }
    }
    // ---- epilogue: bias + store bf16
#pragma unroll
    for (int nt = 0; nt < 8; ++nt) {
        float bv = bias[nt * 16 + ml];
#pragma unroll
        for (int mt = 0; mt < 2; ++mt) {
            int mr0 = m0 + w * 32 + mt * 16 + kg * 4;
#pragma unroll
            for (int rr = 0; rr < 4; ++rr) {
                int mr = mr0 + rr;
                if (mr < M) C[(size_t)mr * FOUT + nt * 16 + ml] = f2bf(acc[mt][nt][rr] + bv);
            }
        }
    }
}

// ---------------------------------------------------------------- aggregation (CSR, bf16 gather)
// out[i] = dinv[i]^2 * h[i] + sum_{s in N(i)} dinv[i]*dinv[s]*h[s]
// One node per 32-lane group (32 x ushort4 = 128 bf16 feats = 256B/row),
// edge loop unrolled x4 with independent accumulators (MLP).
__global__ __launch_bounds__(256) void agg_kernel(const ushort* __restrict__ h,
                                                  const float* __restrict__ dinv,
                                                  const int* __restrict__ offsets,
                                                  const int* __restrict__ srcs,
                                                  float* __restrict__ out, int Nn) {
    const int sub  = threadIdx.x >> 5;
    const int lane = threadIdx.x & 31;
    int node = blockIdx.x * 8 + sub;
    if (node >= Nn) return;
    const ushort4* __restrict__ h4 = (const ushort4*)h;  // 32 ushort4 per row
    float di = dinv[node];
    ushort4 hv = h4[(size_t)node * 32 + lane];
    float sw = di * di;
    float4 a0, a1, a2, a3;
    a0.x = sw * bf2f(hv.x); a0.y = sw * bf2f(hv.y);
    a0.z = sw * bf2f(hv.z); a0.w = sw * bf2f(hv.w);
    a1 = make_float4(0.f, 0.f, 0.f, 0.f);
    a2 = a1;
    a3 = a1;
    int beg = offsets[node], end = offsets[node + 1];
    int e = beg;
    for (; e + 4 <= end; e += 4) {
        int i0 = srcs[e], i1 = srcs[e + 1], i2 = srcs[e + 2], i3 = srcs[e + 3];
        float n0 = di * dinv[i0], n1 = di * dinv[i1];
        float n2 = di * dinv[i2], n3 = di * dinv[i3];
        ushort4 v0 = h4[(size_t)i0 * 32 + lane];
        ushort4 v1 = h4[(size_t)i1 * 32 + lane];
        ushort4 v2 = h4[(size_t)i2 * 32 + lane];
        ushort4 v3 = h4[(size_t)i3 * 32 + lane];
        a0.x = fmaf(n0, bf2f(v0.x), a0.x); a0.y = fmaf(n0, bf2f(v0.y), a0.y);
        a0.z = fmaf(n0, bf2f(v0.z), a0.z); a0.w = fmaf(n0, bf2f(v0.w), a0.w);
        a1.x = fmaf(n1, bf2f(v1.x), a1.x); a1.y = fmaf(n1, bf2f(v1.y), a1.y);
        a1.z = fmaf(n1, bf2f(v1.z), a1.z); a1.w = fmaf(n1, bf2f(v1.w), a1.w);
        a2.x = fmaf(n2, bf2f(v2.x), a2.x); a2.y = fmaf(n2, bf2f(v2.y), a2.y);
        a2.z = fmaf(n2, bf2f(v2.z), a2.z); a2.w = fmaf(n2, bf2f(v2.w), a2.w);
        a3.x = fmaf(n3, bf2f(v3.x), a3.x); a3.y = fmaf(n3, bf2f(v3.y), a3.y);
        a3.z = fmaf(n3, bf2f(v3.z), a3.z); a3.w = fmaf(n3, bf2f(v3.w), a3.w);
    }
    for (; e < end; ++e) {
        int s = srcs[e];
        float n = di * dinv[s];
        ushort4 v = h4[(size_t)s * 32 + lane];
        a0.x = fmaf(n, bf2f(v.x), a0.x); a0.y = fmaf(n, bf2f(v.y), a0.y);
        a0.z = fmaf(n, bf2f(v.z), a0.z); a0.w = fmaf(n, bf2f(v.w), a0.w);
    }
    a0.x += a1.x + a2.x + a3.x;
    a0.y += a1.y + a2.y + a3.y;
    a0.z += a1.z + a2.z + a3.z;
    a0.w += a1.w + a2.w + a3.w;
    float4* __restrict__ o4 = (float4*)out;
    o4[(size_t)node * 32 + lane] = a0;
}

// ---------------------------------------------------------------- BN stats
__global__ __launch_bounds__(256) void bn_stats_kernel(const float* __restrict__ x,
                                                       float* __restrict__ sum,
                                                       float* __restrict__ sumsq, int Nn) {
    const int T = gridDim.x * 256;
    int tid = blockIdx.x * 256 + threadIdx.x;
    float s1 = 0.f, s2 = 0.f;
    for (size_t i = tid; i < (size_t)Nn * FOUT; i += T) {
        float v = x[i];
        s1 += v;
        s2 += v * v;
    }
    __shared__ float sh1[256], sh2[256];
    sh1[threadIdx.x] = s1;
    sh2[threadIdx.x] = s2;
    __syncthreads();
    if (threadIdx.x < 128) {
        s1 = sh1[threadIdx.x] + sh1[threadIdx.x + 128];
        s2 = sh2[threadIdx.x] + sh2[threadIdx.x + 128];
        int f = (blockIdx.x * 256 + threadIdx.x) & 127;
        atomicAdd(&sum[f], s1);
        atomicAdd(&sumsq[f], s2);
    }
}

// ---------------------------------------------------------------- BN apply + leaky relu (final, in place)
__global__ __launch_bounds__(256) void bn_apply_kernel(float* __restrict__ x,
                                                       const float* __restrict__ sum,
                                                       const float* __restrict__ sumsq,
                                                       const float* __restrict__ gamma,
                                                       const float* __restrict__ beta, int Nn) {
    size_t i = (size_t)blockIdx.x * 256 + threadIdx.x;
    if (i >= (size_t)Nn * FOUT) return;
    int f = (int)(i & 127);
    const float invN = 1.0f / (float)NODES;
    float mu  = sum[f] * invN;
    float var = sumsq[f] * invN - mu * mu;
    float sc  = gamma[f] * rsqrtf(var + EPS);
    float v   = (x[i] - mu) * sc + beta[f];
    x[i] = (v >= 0.f) ? v : SLOPE * v;
}

// ================================================================ launch
extern "C" void kernel_launch(void* const* d_in, const int* in_sizes, int n_in,
                              void* d_out, int out_size, void* d_ws, size_t ws_size,
                              hipStream_t stream) {
    const float* x  = (const float*)d_in[0];
    const int*   ei = (const int*)d_in[1];
    const float* W1 = (const float*)d_in[2];
    const float* b1 = (const float*)d_in[3];
    const float* W2 = (const float*)d_in[4];
    const float* b2 = (const float*)d_in[5];
    const float* g1 = (const float*)d_in[6];
    const float* be1 = (const float*)d_in[7];
    const float* g2 = (const float*)d_in[8];
    const float* be2 = (const float*)d_in[9];
    float* out = (float*)d_out;

    const int E = in_sizes[1] / 2;
    const int* erow = ei;
    const int* ecol = ei + E;

    // ---- workspace layout (offsets unchanged from round 9; bufA now bf16,
    //      using only the first 12.8MB of its 25.6MB region)
    ushort* bufA    = (ushort*)d_ws;                         // 6.4M bf16 (h)
    float* dinv     = (float*)d_ws + (size_t)NODES * FOUT;   // 50,000 f
    int*   deg      = (int*)(dinv + NODES);                  // 50,000 i  } zero region
    int*   cursor   = deg + NODES;                           // 50,000 i  (reused as Bt)
    float* colsumA  = (float*)(cursor + NODES);              // 128
    float* colsqA   = colsumA + 128;                         // 128
    float* colsumB  = colsqA + 128;                          // 128
    float* colsqB   = colsumB + 128;                         // 128       } zero region end
    int*   offsets  = (int*)(colsqB + 128);                  // 50,001 i
    int*   srcs     = offsets + (NODES + 1);                 // E i
    int*   partials = srcs + E;                              // 98 i
    int*   partpre  = partials + SCAN_NB;                    // 98 i
    // scale/shift live in bufA's freed second half (13.2MB into ws, well past
    // the 12.8MB of bf16 h data; no footprint growth)
    float* scaleA   = (float*)d_ws + 3300000;                // 128 f
    float* shiftA   = scaleA + 128;                          // 128 f
    // Bt aliases cursor region (dead after fill; wcvt runs after fill)
    ushort* Bt1 = (ushort*)cursor;                           // 128*256 bf16
    ushort* Bt2 = Bt1 + 128 * FIN;                           // 128*128 bf16

    size_t zero_bytes = (size_t)(2 * NODES) * sizeof(int) + 4 * 128 * sizeof(float);
    hipMemsetAsync(deg, 0, zero_bytes, stream);

    int egrid = (E + 255) / 256;
    deg_kernel<<<egrid, 256, 0, stream>>>(ecol, E, deg);
    scan1_kernel<<<SCAN_NB, 256, 0, stream>>>(deg, partials, NODES);
    scan2_kernel<<<1, 128, 0, stream>>>(partials, partpre, &offsets[NODES], E);
    scan3_kernel<<<SCAN_NB, 256, 0, stream>>>(deg, partpre, offsets, dinv, NODES);
    fill_kernel<<<egrid, 256, 0, stream>>>(erow, ecol, E, offsets, cursor, srcs);
    wcvt_kernel<FIN><<<(128 * FIN) / 256, 256, 0, stream>>>(W1, Bt1);
    wcvt_kernel<FOUT><<<(128 * FOUT) / 256, 256, 0, stream>>>(W2, Bt2);

    const int mg = (NODES + 127) / 128;                 // 391 GEMM blocks
    const int ag = (NODES + 7) / 8;                     // 6250 agg blocks
    const int eg = ((size_t)NODES * FOUT + 255) / 256;  // 25000 elementwise blocks

    // ---- layer 1
    gemm_mfma_kernel<FIN, false><<<mg, 256, 0, stream>>>(x, Bt1, b1, nullptr, nullptr, bufA, NODES);
    agg_kernel<<<ag, 256, 0, stream>>>(bufA, dinv, offsets, srcs, out, NODES);
    bn_stats_kernel<<<256, 256, 0, stream>>>(out, colsumA, colsqA, NODES);
    bn_finalize_kernel<<<1, 128, 0, stream>>>(colsumA, colsqA, g1, be1, scaleA, shiftA);

    // ---- layer 2 (BN1+LeakyReLU fused into A-staging)
    gemm_mfma_kernel<FOUT, true><<<mg, 256, 0, stream>>>(out, Bt2, b2, scaleA, shiftA, bufA, NODES);
    agg_kernel<<<ag, 256, 0, stream>>>(bufA, dinv, offsets, srcs, out, NODES);
    bn_stats_kernel<<<256, 256, 0, stream>>>(out, colsumB, colsqB, NODES);
    bn_apply_kernel<<<eg, 256, 0, stream>>>(out, colsumB, colsqB, g2, be2, NODES);
}